// Round 4
// baseline (664.386 us; speedup 1.0000x reference)
//
#include <hip/hip_runtime.h>
#include <hip/hip_bf16.h>

static constexpr int NG = 512;   // NUM_GRAPHS

typedef __attribute__((ext_vector_type(8))) short bf16x8;
typedef __attribute__((ext_vector_type(4))) float f32x4;

__device__ inline ushort f2bf(float f) {
    union { float f; uint u; } v; v.f = f;
    uint r = (v.u + 0x7FFF + ((v.u >> 16) & 1)) >> 16;   // RNE
    return (ushort)r;
}
__device__ inline float bf2f(ushort h) {
    union { uint u; float f; } v; v.u = (uint)h << 16;
    return v.f;
}

// ---------------- degree / dinv ----------------
__global__ void degree_kernel(const int* __restrict__ col, int* __restrict__ degi, int E) {
    int e = blockIdx.x * blockDim.x + threadIdx.x;
    if (e < E) atomicAdd(&degi[col[e]], 1);
}

__global__ void dinv_kernel(const int* __restrict__ degi, float* __restrict__ dinv, int n) {
    int i = blockIdx.x * blockDim.x + threadIdx.x;
    if (i < n) dinv[i] = rsqrtf((float)(degi[i] + 1));  // +1 self loop; always > 0
}

// ---------------- hierarchical exclusive scan ----------------
__global__ __launch_bounds__(256) void blockreduce_kernel(const int* __restrict__ deg,
                                                          int* __restrict__ blocksums, int n) {
    __shared__ int lds[256];
    int b = blockIdx.x;
    int base = b * 1024;
    int s = 0;
    for (int j = threadIdx.x; j < 1024; j += 256) {
        int i = base + j;
        s += (i < n) ? deg[i] : 0;
    }
    lds[threadIdx.x] = s;
    __syncthreads();
    #pragma unroll
    for (int off = 128; off > 0; off >>= 1) {
        if ((int)threadIdx.x < off) lds[threadIdx.x] += lds[threadIdx.x + off];
        __syncthreads();
    }
    if (threadIdx.x == 0) blocksums[b] = lds[0];
}

__global__ __launch_bounds__(128) void blockscan_kernel(const int* __restrict__ blocksums,
                                                        int* __restrict__ blockoffs,
                                                        int* __restrict__ total_out, int nb) {
    __shared__ int lds[128];
    int v = ((int)threadIdx.x < nb) ? blocksums[threadIdx.x] : 0;
    lds[threadIdx.x] = v;
    __syncthreads();
    #pragma unroll
    for (int off = 1; off < 128; off <<= 1) {
        int t = ((int)threadIdx.x >= off) ? lds[threadIdx.x - off] : 0;
        __syncthreads();
        lds[threadIdx.x] += t;
        __syncthreads();
    }
    if ((int)threadIdx.x < nb) blockoffs[threadIdx.x] = lds[threadIdx.x] - v;  // exclusive
    if (threadIdx.x == 0) total_out[0] = lds[127];
}

__global__ __launch_bounds__(1024) void scanapply_kernel(const int* __restrict__ deg,
                                                         const int* __restrict__ blockoffs,
                                                         int* __restrict__ offsets, int n) {
    __shared__ int lds[1024];
    int b = blockIdx.x;
    int i = b * 1024 + (int)threadIdx.x;
    int v = (i < n) ? deg[i] : 0;
    lds[threadIdx.x] = v;
    __syncthreads();
    #pragma unroll
    for (int off = 1; off < 1024; off <<= 1) {
        int t = ((int)threadIdx.x >= off) ? lds[threadIdx.x - off] : 0;
        __syncthreads();
        lds[threadIdx.x] += t;
        __syncthreads();
    }
    if (i < n) offsets[i] = blockoffs[b] + lds[threadIdx.x] - v;
}

// ---------------- scatter edges into CSR-by-destination (src only) ----------------
__global__ void scatter_kernel(const int* __restrict__ row, const int* __restrict__ col,
                               const int* __restrict__ offsets,
                               int* __restrict__ cursor, int* __restrict__ srcs, int E) {
    int e = blockIdx.x * blockDim.x + threadIdx.x;
    if (e >= E) return;
    int s = row[e], d = col[e];
    int pos = offsets[d] + atomicAdd(&cursor[d], 1);
    srcs[pos] = s;
}

// ---------------- f32 -> bf16 convert (x) ----------------
__global__ void f2bf_kernel(const float* __restrict__ in, ushort* __restrict__ out, int n4) {
    int i = blockIdx.x * blockDim.x + threadIdx.x;   // one float4 per thread
    if (i >= n4) return;
    float4 v = ((const float4*)in)[i];
    ushort4 o;
    o.x = f2bf(v.x); o.y = f2bf(v.y); o.z = f2bf(v.z); o.w = f2bf(v.w);
    ((ushort4*)out)[i] = o;
}

// ---------------- pack W (f32 row-major 128x128) into MFMA B-fragment layout ----------------
__global__ __launch_bounds__(256) void packW_kernel(const float* __restrict__ W,
                                                    ushort* __restrict__ Wp) {
    int idx = blockIdx.x * 256 + threadIdx.x;   // 0..2047
    int lane = idx & 63;
    int nt = (idx >> 6) & 7;
    int kt = idx >> 9;
    int col = nt * 16 + (lane & 15);
    int kbase = kt * 32 + (lane >> 4) * 8;
    ushort* dst = Wp + (size_t)idx * 8;
    #pragma unroll
    for (int j = 0; j < 8; j++)
        dst[j] = f2bf(W[(size_t)(kbase + j) * 128 + col]);
}

// ---------------- MFMA GEMM: C[Mx128](bf16) = A[Mx128](bf16) * W(packed bf16) ---------
__global__ __launch_bounds__(256) void gemm_mfma_kernel(const ushort* __restrict__ A,
                                                        const ushort* __restrict__ Wp,
                                                        ushort* __restrict__ C, int M) {
    int wave = threadIdx.x >> 6;
    int lane = threadIdx.x & 63;
    int r0 = blockIdx.x * 128 + wave * 32;
    if (r0 >= M) return;
    const int lrow = lane & 15;
    const int koff = (lane >> 4) * 8;
    f32x4 acc[2][8] = {};
    #pragma unroll
    for (int kt = 0; kt < 4; kt++) {
        bf16x8 a[2];
        #pragma unroll
        for (int m = 0; m < 2; m++) {
            int r = r0 + 16 * m + lrow;
            r = (r < M) ? r : (M - 1);
            a[m] = *(const bf16x8*)(A + (size_t)r * 128 + kt * 32 + koff);
        }
        #pragma unroll
        for (int nt = 0; nt < 8; nt++) {
            bf16x8 b = *(const bf16x8*)(Wp + ((size_t)(kt * 8 + nt) * 64 + lane) * 8);
            acc[0][nt] = __builtin_amdgcn_mfma_f32_16x16x32_bf16(a[0], b, acc[0][nt], 0, 0, 0);
            acc[1][nt] = __builtin_amdgcn_mfma_f32_16x16x32_bf16(a[1], b, acc[1][nt], 0, 0, 0);
        }
    }
    // C/D layout: col = lane&15, row = (lane>>4)*4 + reg   [verified m89]
    #pragma unroll
    for (int m = 0; m < 2; m++) {
        int rbase = r0 + 16 * m + (lane >> 4) * 4;
        int c0 = lane & 15;
        #pragma unroll
        for (int nt = 0; nt < 8; nt++) {
            #pragma unroll
            for (int r = 0; r < 4; r++) {
                int rr = rbase + r;
                if (rr < M) C[(size_t)rr * 128 + nt * 16 + c0] = f2bf(acc[m][nt][r]);
            }
        }
    }
}

// ---------------- aggregation (bf16 h, f32 accumulate, bf16 out, norm on the fly) -----
__global__ __launch_bounds__(256) void agg_kernel(const ushort* __restrict__ h,
                                                  const int* __restrict__ offsets,
                                                  const int* __restrict__ srcs,
                                                  const float* __restrict__ dinv,
                                                  const float* __restrict__ bias,
                                                  ushort* __restrict__ out, int n) {
    int wid  = (int)((blockIdx.x * blockDim.x + threadIdx.x) >> 6);
    int lane = threadIdx.x & 63;
    if (wid >= n) return;
    int s0 = offsets[wid], s1 = offsets[wid + 1];
    float di = dinv[wid];
    uint hv = ((const uint*)(h + (size_t)wid * 128))[lane];
    float wself = di * di;
    float ax = wself * bf2f((ushort)(hv & 0xFFFF));
    float ay = wself * bf2f((ushort)(hv >> 16));
    #pragma unroll 2
    for (int e = s0; e < s1; e++) {
        int s   = srcs[e];
        float w = dinv[s] * di;
        uint g = ((const uint*)(h + (size_t)s * 128))[lane];
        ax = fmaf(w, bf2f((ushort)(g & 0xFFFF)), ax);
        ay = fmaf(w, bf2f((ushort)(g >> 16)), ay);
    }
    ax += bias[2 * lane];
    ay += bias[2 * lane + 1];
    ax = fmaxf(ax, 0.0f);
    ay = fmaxf(ay, 0.0f);
    ((uint*)(out + (size_t)wid * 128))[lane] = (uint)f2bf(ax) | ((uint)f2bf(ay) << 16);
}

// ---------------- mean pool per graph (batch sorted, bf16 in, f32 out) ----------------
__global__ __launch_bounds__(128) void pool_kernel(const ushort* __restrict__ h,
                                                   const int* __restrict__ batch,
                                                   float* __restrict__ pooled, int n) {
    int g = blockIdx.x;
    int lo = 0, hi = n;
    while (lo < hi) { int mid = (lo + hi) >> 1; if (batch[mid] < g) lo = mid + 1; else hi = mid; }
    int start = lo;
    lo = 0; hi = n;
    while (lo < hi) { int mid = (lo + hi) >> 1; if (batch[mid] < g + 1) lo = mid + 1; else hi = mid; }
    int end = lo;
    int c = threadIdx.x;
    float acc = 0.0f;
    for (int i = start; i < end; i++) acc += bf2f(h[(size_t)i * 128 + c]);
    float cnt = (float)(end - start);
    pooled[(size_t)g * 128 + c] = acc / fmaxf(cnt, 1.0f);
}

// ---------------- MLP ----------------
__global__ __launch_bounds__(64) void mlp_kernel(const float* __restrict__ pooled,
                                                 const float* __restrict__ Wm1,
                                                 const float* __restrict__ bm1,
                                                 const float* __restrict__ Wm2,
                                                 const float* __restrict__ bm2,
                                                 float* __restrict__ out) {
    int g = blockIdx.x;
    __shared__ float p[128];
    __shared__ float z[64];
    int t = threadIdx.x;
    p[t]      = pooled[(size_t)g * 128 + t];
    p[t + 64] = pooled[(size_t)g * 128 + 64 + t];
    __syncthreads();
    float acc = bm1[t];
    #pragma unroll 8
    for (int k = 0; k < 128; k++) acc = fmaf(p[k], Wm1[k * 64 + t], acc);
    z[t] = fmaxf(acc, 0.0f);
    __syncthreads();
    if (t < 32) {
        float o = bm2[t];
        #pragma unroll 8
        for (int k = 0; k < 64; k++) o = fmaf(z[k], Wm2[k * 32 + t], o);
        out[(size_t)g * 32 + t] = o;
    }
}

extern "C" void kernel_launch(void* const* d_in, const int* in_sizes, int n_in,
                              void* d_out, int out_size, void* d_ws, size_t ws_size,
                              hipStream_t stream) {
    const float* x    = (const float*)d_in[0];
    const int*   ei   = (const int*)d_in[1];
    const int*   batch= (const int*)d_in[2];
    const float* W1   = (const float*)d_in[3];
    const float* b1   = (const float*)d_in[4];
    const float* W2   = (const float*)d_in[5];
    const float* b2   = (const float*)d_in[6];
    const float* W3   = (const float*)d_in[7];
    const float* b3   = (const float*)d_in[8];
    const float* Wm1  = (const float*)d_in[9];
    const float* bm1  = (const float*)d_in[10];
    const float* Wm2  = (const float*)d_in[11];
    const float* bm2  = (const float*)d_in[12];
    float* out = (float*)d_out;

    int N = in_sizes[0] / 128;
    int E = in_sizes[1] / 2;
    const int* row = ei;       // sources
    const int* col = ei + E;   // targets

    char* w = (char*)d_ws;
    auto alloc = [&](size_t bytes) -> char* {
        char* p = w;
        w += (bytes + 255) & ~(size_t)255;
        return p;
    };
    int*    degi    = (int*)   alloc((size_t)N * 4);
    int*    offs    = (int*)   alloc((size_t)(N + 1) * 4);
    int*    cursor  = (int*)   alloc((size_t)N * 4);
    float*  dinv    = (float*) alloc((size_t)N * 4);
    int*    srcs    = (int*)   alloc((size_t)E * 4);
    ushort* x_bf    = (ushort*)alloc((size_t)N * 128 * 2);
    ushort* hA      = (ushort*)alloc((size_t)N * 128 * 2);
    ushort* hB      = (ushort*)alloc((size_t)N * 128 * 2);
    float*  pooled  = (float*) alloc((size_t)NG * 128 * 4);
    int*    bsums   = (int*)   alloc((size_t)128 * 4);
    int*    boffs   = (int*)   alloc((size_t)128 * 4);
    ushort* Wp1     = (ushort*)alloc((size_t)128 * 128 * 2);
    ushort* Wp2     = (ushort*)alloc((size_t)128 * 128 * 2);
    ushort* Wp3     = (ushort*)alloc((size_t)128 * 128 * 2);
    (void)ws_size; (void)n_in; (void)out_size;

    hipMemsetAsync(degi,   0, (size_t)N * 4, stream);
    hipMemsetAsync(cursor, 0, (size_t)N * 4, stream);

    int NB = (N + 1023) / 1024;   // 98 <= 128

    degree_kernel<<<(E + 255) / 256, 256, 0, stream>>>(col, degi, E);
    dinv_kernel<<<(N + 255) / 256, 256, 0, stream>>>(degi, dinv, N);
    blockreduce_kernel<<<NB, 256, 0, stream>>>(degi, bsums, N);
    blockscan_kernel<<<1, 128, 0, stream>>>(bsums, boffs, offs + N, NB);
    scanapply_kernel<<<NB, 1024, 0, stream>>>(degi, boffs, offs, N);
    scatter_kernel<<<(E + 255) / 256, 256, 0, stream>>>(row, col, offs, cursor, srcs, E);

    // conversions / weight packing
    int n4 = N * 128 / 4;
    f2bf_kernel<<<(n4 + 255) / 256, 256, 0, stream>>>(x, x_bf, n4);
    packW_kernel<<<8, 256, 0, stream>>>(W1, Wp1);
    packW_kernel<<<8, 256, 0, stream>>>(W2, Wp2);
    packW_kernel<<<8, 256, 0, stream>>>(W3, Wp3);

    int gemmBlocks = (N + 127) / 128;
    int aggBlocks  = (N + 3) / 4;   // 4 waves/block, wave per node

    gemm_mfma_kernel<<<gemmBlocks, 256, 0, stream>>>(x_bf, Wp1, hA, N);
    agg_kernel<<<aggBlocks, 256, 0, stream>>>(hA, offs, srcs, dinv, b1, hB, N);

    gemm_mfma_kernel<<<gemmBlocks, 256, 0, stream>>>(hB, Wp2, hA, N);
    agg_kernel<<<aggBlocks, 256, 0, stream>>>(hA, offs, srcs, dinv, b2, hB, N);

    gemm_mfma_kernel<<<gemmBlocks, 256, 0, stream>>>(hB, Wp3, hA, N);
    agg_kernel<<<aggBlocks, 256, 0, stream>>>(hA, offs, srcs, dinv, b3, hB, N);

    pool_kernel<<<NG, 128, 0, stream>>>(hB, batch, pooled, N);
    mlp_kernel<<<NG, 64, 0, stream>>>(pooled, Wm1, bm1, Wm2, bm2, out);
}

// Round 5
// 590.043 us; speedup vs baseline: 1.1260x; 1.1260x over previous
//
#include <hip/hip_runtime.h>
#include <hip/hip_bf16.h>

static constexpr int NG = 512;   // NUM_GRAPHS

typedef __attribute__((ext_vector_type(8))) short bf16x8;
typedef __attribute__((ext_vector_type(4))) float f32x4;

__device__ inline ushort f2bf(float f) {
    union { float f; uint u; } v; v.f = f;
    uint r = (v.u + 0x7FFF + ((v.u >> 16) & 1)) >> 16;   // RNE
    return (ushort)r;
}
__device__ inline float bf2f(ushort h) {
    union { uint u; float f; } v; v.u = (uint)h << 16;
    return v.f;
}

// ---------------- degree / dinv ----------------
__global__ void degree_kernel(const int* __restrict__ col, int* __restrict__ degi, int E) {
    int e = blockIdx.x * blockDim.x + threadIdx.x;
    if (e < E) atomicAdd(&degi[col[e]], 1);
}

__global__ void dinv_kernel(const int* __restrict__ degi, float* __restrict__ dinv, int n) {
    int i = blockIdx.x * blockDim.x + threadIdx.x;
    if (i < n) dinv[i] = rsqrtf((float)(degi[i] + 1));  // +1 self loop; always > 0
}

// ---------------- hierarchical exclusive scan ----------------
__global__ __launch_bounds__(256) void blockreduce_kernel(const int* __restrict__ deg,
                                                          int* __restrict__ blocksums, int n) {
    __shared__ int lds[256];
    int b = blockIdx.x;
    int base = b * 1024;
    int s = 0;
    for (int j = threadIdx.x; j < 1024; j += 256) {
        int i = base + j;
        s += (i < n) ? deg[i] : 0;
    }
    lds[threadIdx.x] = s;
    __syncthreads();
    #pragma unroll
    for (int off = 128; off > 0; off >>= 1) {
        if ((int)threadIdx.x < off) lds[threadIdx.x] += lds[threadIdx.x + off];
        __syncthreads();
    }
    if (threadIdx.x == 0) blocksums[b] = lds[0];
}

__global__ __launch_bounds__(128) void blockscan_kernel(const int* __restrict__ blocksums,
                                                        int* __restrict__ blockoffs,
                                                        int* __restrict__ total_out, int nb) {
    __shared__ int lds[128];
    int v = ((int)threadIdx.x < nb) ? blocksums[threadIdx.x] : 0;
    lds[threadIdx.x] = v;
    __syncthreads();
    #pragma unroll
    for (int off = 1; off < 128; off <<= 1) {
        int t = ((int)threadIdx.x >= off) ? lds[threadIdx.x - off] : 0;
        __syncthreads();
        lds[threadIdx.x] += t;
        __syncthreads();
    }
    if ((int)threadIdx.x < nb) blockoffs[threadIdx.x] = lds[threadIdx.x] - v;  // exclusive
    if (threadIdx.x == 0) total_out[0] = lds[127];
}

__global__ __launch_bounds__(1024) void scanapply_kernel(const int* __restrict__ deg,
                                                         const int* __restrict__ blockoffs,
                                                         int* __restrict__ offsets, int n) {
    __shared__ int lds[1024];
    int b = blockIdx.x;
    int i = b * 1024 + (int)threadIdx.x;
    int v = (i < n) ? deg[i] : 0;
    lds[threadIdx.x] = v;
    __syncthreads();
    #pragma unroll
    for (int off = 1; off < 1024; off <<= 1) {
        int t = ((int)threadIdx.x >= off) ? lds[threadIdx.x - off] : 0;
        __syncthreads();
        lds[threadIdx.x] += t;
        __syncthreads();
    }
    if (i < n) offsets[i] = blockoffs[b] + lds[threadIdx.x] - v;
}

// ---------------- bucketed two-pass CSR build ----------------
// bucket b = dst window [b*512, (b+1)*512); bucket base in edge space = offs[b*512]
__global__ __launch_bounds__(256) void cursorinit_kernel(const int* __restrict__ offs,
                                                         int* __restrict__ cursor, int nbuk) {
    int b = blockIdx.x * 256 + threadIdx.x;
    if (b < nbuk) cursor[b] = offs[b << 9];
}

// pass 1: partition edges into dst-buckets, packed (src<<9)|dst_local
static constexpr int EPW = 4096;   // edges per workgroup (16 per thread)
__global__ __launch_bounds__(256) void partition_kernel(const int* __restrict__ row,
                                                        const int* __restrict__ col,
                                                        int* __restrict__ cursor,
                                                        uint* __restrict__ pairs,
                                                        int E, int nbuk) {
    __shared__ int cnt[256];    // nbuk <= 256 (N <= 128K)
    __shared__ int gbase[256];
    int tid = threadIdx.x;
    int base = blockIdx.x * EPW;
    for (int b = tid; b < nbuk; b += 256) cnt[b] = 0;
    __syncthreads();
    int rank[16];
    #pragma unroll
    for (int j = 0; j < 16; j++) {
        int e = base + j * 256 + tid;
        rank[j] = (e < E) ? atomicAdd(&cnt[col[e] >> 9], 1) : 0;
    }
    __syncthreads();
    for (int b = tid; b < nbuk; b += 256)
        gbase[b] = cnt[b] ? atomicAdd(&cursor[b], cnt[b]) : 0;
    __syncthreads();
    #pragma unroll
    for (int j = 0; j < 16; j++) {
        int e = base + j * 256 + tid;
        if (e < E) {
            int d = col[e];
            int b = d >> 9;
            pairs[gbase[b] + rank[j]] = ((uint)row[e] << 9) | (uint)(d & 511);
        }
    }
}

// pass 2: place within bucket; CSR output region per bucket ~65KB -> L2-coalesced writes
__global__ __launch_bounds__(256) void place_kernel(const uint* __restrict__ pairs,
                                                    const int* __restrict__ offs,
                                                    const float* __restrict__ dinv,
                                                    int* __restrict__ srcs,
                                                    float* __restrict__ wgts, int N) {
    __shared__ int cur[512];
    int nodebase = blockIdx.x << 9;
    int nend = min(nodebase + 512, N);
    int lo = offs[nodebase], hi = offs[nend];
    cur[threadIdx.x] = 0;
    cur[threadIdx.x + 256] = 0;
    __syncthreads();
    for (int e = lo + (int)threadIdx.x; e < hi; e += 256) {
        uint p = pairs[e];
        int dloc = (int)(p & 511);
        int s = (int)(p >> 9);
        int d = nodebase + dloc;
        int pos = offs[d] + atomicAdd(&cur[dloc], 1);
        srcs[pos] = s;
        wgts[pos] = dinv[s] * dinv[d];
    }
}

// ---------------- f32 -> bf16 convert (x) ----------------
__global__ void f2bf_kernel(const float* __restrict__ in, ushort* __restrict__ out, int n4) {
    int i = blockIdx.x * blockDim.x + threadIdx.x;   // one float4 per thread
    if (i >= n4) return;
    float4 v = ((const float4*)in)[i];
    ushort4 o;
    o.x = f2bf(v.x); o.y = f2bf(v.y); o.z = f2bf(v.z); o.w = f2bf(v.w);
    ((ushort4*)out)[i] = o;
}

// ---------------- pack W (f32 row-major 128x128) into MFMA B-fragment layout ----------------
__global__ __launch_bounds__(256) void packW_kernel(const float* __restrict__ W,
                                                    ushort* __restrict__ Wp) {
    int idx = blockIdx.x * 256 + threadIdx.x;   // 0..2047
    int lane = idx & 63;
    int nt = (idx >> 6) & 7;
    int kt = idx >> 9;
    int col = nt * 16 + (lane & 15);
    int kbase = kt * 32 + (lane >> 4) * 8;
    ushort* dst = Wp + (size_t)idx * 8;
    #pragma unroll
    for (int j = 0; j < 8; j++)
        dst[j] = f2bf(W[(size_t)(kbase + j) * 128 + col]);
}

// ---------------- MFMA GEMM: C[Mx128](bf16) = A[Mx128](bf16) * W(packed bf16) ---------
__global__ __launch_bounds__(256) void gemm_mfma_kernel(const ushort* __restrict__ A,
                                                        const ushort* __restrict__ Wp,
                                                        ushort* __restrict__ C, int M) {
    int wave = threadIdx.x >> 6;
    int lane = threadIdx.x & 63;
    int r0 = blockIdx.x * 128 + wave * 32;
    if (r0 >= M) return;
    const int lrow = lane & 15;
    const int koff = (lane >> 4) * 8;
    f32x4 acc[2][8] = {};
    #pragma unroll
    for (int kt = 0; kt < 4; kt++) {
        bf16x8 a[2];
        #pragma unroll
        for (int m = 0; m < 2; m++) {
            int r = r0 + 16 * m + lrow;
            r = (r < M) ? r : (M - 1);
            a[m] = *(const bf16x8*)(A + (size_t)r * 128 + kt * 32 + koff);
        }
        #pragma unroll
        for (int nt = 0; nt < 8; nt++) {
            bf16x8 b = *(const bf16x8*)(Wp + ((size_t)(kt * 8 + nt) * 64 + lane) * 8);
            acc[0][nt] = __builtin_amdgcn_mfma_f32_16x16x32_bf16(a[0], b, acc[0][nt], 0, 0, 0);
            acc[1][nt] = __builtin_amdgcn_mfma_f32_16x16x32_bf16(a[1], b, acc[1][nt], 0, 0, 0);
        }
    }
    // C/D layout: col = lane&15, row = (lane>>4)*4 + reg   [verified m89]
    #pragma unroll
    for (int m = 0; m < 2; m++) {
        int rbase = r0 + 16 * m + (lane >> 4) * 4;
        int c0 = lane & 15;
        #pragma unroll
        for (int nt = 0; nt < 8; nt++) {
            #pragma unroll
            for (int r = 0; r < 4; r++) {
                int rr = rbase + r;
                if (rr < M) C[(size_t)rr * 128 + nt * 16 + c0] = f2bf(acc[m][nt][r]);
            }
        }
    }
}

// ---------------- aggregation (bf16 h, f32 accumulate, bf16 out) ----------------
__global__ __launch_bounds__(256) void agg_kernel(const ushort* __restrict__ h,
                                                  const int* __restrict__ offsets,
                                                  const int* __restrict__ srcs,
                                                  const float* __restrict__ wgts,
                                                  const float* __restrict__ dinv,
                                                  const float* __restrict__ bias,
                                                  ushort* __restrict__ out, int n) {
    int wid  = (int)((blockIdx.x * blockDim.x + threadIdx.x) >> 6);
    int lane = threadIdx.x & 63;
    if (wid >= n) return;
    int s0 = offsets[wid], s1 = offsets[wid + 1];
    float di = dinv[wid];
    uint hv = ((const uint*)(h + (size_t)wid * 128))[lane];
    float wself = di * di;
    float ax = wself * bf2f((ushort)(hv & 0xFFFF));
    float ay = wself * bf2f((ushort)(hv >> 16));
    #pragma unroll 2
    for (int e = s0; e < s1; e++) {
        int s   = srcs[e];
        float w = wgts[e];
        uint g = ((const uint*)(h + (size_t)s * 128))[lane];
        ax = fmaf(w, bf2f((ushort)(g & 0xFFFF)), ax);
        ay = fmaf(w, bf2f((ushort)(g >> 16)), ay);
    }
    ax += bias[2 * lane];
    ay += bias[2 * lane + 1];
    ax = fmaxf(ax, 0.0f);
    ay = fmaxf(ay, 0.0f);
    ((uint*)(out + (size_t)wid * 128))[lane] = (uint)f2bf(ax) | ((uint)f2bf(ay) << 16);
}

// ---------------- mean pool per graph (batch sorted, bf16 in, f32 out) ----------------
__global__ __launch_bounds__(128) void pool_kernel(const ushort* __restrict__ h,
                                                   const int* __restrict__ batch,
                                                   float* __restrict__ pooled, int n) {
    int g = blockIdx.x;
    int lo = 0, hi = n;
    while (lo < hi) { int mid = (lo + hi) >> 1; if (batch[mid] < g) lo = mid + 1; else hi = mid; }
    int start = lo;
    lo = 0; hi = n;
    while (lo < hi) { int mid = (lo + hi) >> 1; if (batch[mid] < g + 1) lo = mid + 1; else hi = mid; }
    int end = lo;
    int c = threadIdx.x;
    float acc = 0.0f;
    for (int i = start; i < end; i++) acc += bf2f(h[(size_t)i * 128 + c]);
    float cnt = (float)(end - start);
    pooled[(size_t)g * 128 + c] = acc / fmaxf(cnt, 1.0f);
}

// ---------------- MLP ----------------
__global__ __launch_bounds__(64) void mlp_kernel(const float* __restrict__ pooled,
                                                 const float* __restrict__ Wm1,
                                                 const float* __restrict__ bm1,
                                                 const float* __restrict__ Wm2,
                                                 const float* __restrict__ bm2,
                                                 float* __restrict__ out) {
    int g = blockIdx.x;
    __shared__ float p[128];
    __shared__ float z[64];
    int t = threadIdx.x;
    p[t]      = pooled[(size_t)g * 128 + t];
    p[t + 64] = pooled[(size_t)g * 128 + 64 + t];
    __syncthreads();
    float acc = bm1[t];
    #pragma unroll 8
    for (int k = 0; k < 128; k++) acc = fmaf(p[k], Wm1[k * 64 + t], acc);
    z[t] = fmaxf(acc, 0.0f);
    __syncthreads();
    if (t < 32) {
        float o = bm2[t];
        #pragma unroll 8
        for (int k = 0; k < 64; k++) o = fmaf(z[k], Wm2[k * 32 + t], o);
        out[(size_t)g * 32 + t] = o;
    }
}

extern "C" void kernel_launch(void* const* d_in, const int* in_sizes, int n_in,
                              void* d_out, int out_size, void* d_ws, size_t ws_size,
                              hipStream_t stream) {
    const float* x    = (const float*)d_in[0];
    const int*   ei   = (const int*)d_in[1];
    const int*   batch= (const int*)d_in[2];
    const float* W1   = (const float*)d_in[3];
    const float* b1   = (const float*)d_in[4];
    const float* W2   = (const float*)d_in[5];
    const float* b2   = (const float*)d_in[6];
    const float* W3   = (const float*)d_in[7];
    const float* b3   = (const float*)d_in[8];
    const float* Wm1  = (const float*)d_in[9];
    const float* bm1  = (const float*)d_in[10];
    const float* Wm2  = (const float*)d_in[11];
    const float* bm2  = (const float*)d_in[12];
    float* out = (float*)d_out;

    int N = in_sizes[0] / 128;
    int E = in_sizes[1] / 2;
    const int* row = ei;       // sources
    const int* col = ei + E;   // targets

    char* w = (char*)d_ws;
    auto alloc = [&](size_t bytes) -> char* {
        char* p = w;
        w += (bytes + 255) & ~(size_t)255;
        return p;
    };
    int*    degi    = (int*)   alloc((size_t)N * 4);
    int*    offs    = (int*)   alloc((size_t)(N + 1) * 4);
    int*    cursor  = (int*)   alloc((size_t)N * 4);
    float*  dinv    = (float*) alloc((size_t)N * 4);
    int*    srcs    = (int*)   alloc((size_t)E * 4);
    float*  wgts    = (float*) alloc((size_t)E * 4);
    uint*   pairs   = (uint*)  alloc((size_t)E * 4);
    ushort* x_bf    = (ushort*)alloc((size_t)N * 128 * 2);
    ushort* hA      = (ushort*)alloc((size_t)N * 128 * 2);
    ushort* hB      = (ushort*)alloc((size_t)N * 128 * 2);
    float*  pooled  = (float*) alloc((size_t)NG * 128 * 4);
    int*    bsums   = (int*)   alloc((size_t)128 * 4);
    int*    boffs   = (int*)   alloc((size_t)128 * 4);
    ushort* Wp1     = (ushort*)alloc((size_t)128 * 128 * 2);
    ushort* Wp2     = (ushort*)alloc((size_t)128 * 128 * 2);
    ushort* Wp3     = (ushort*)alloc((size_t)128 * 128 * 2);
    (void)ws_size; (void)n_in; (void)out_size;

    hipMemsetAsync(degi, 0, (size_t)N * 4, stream);

    int NB   = (N + 1023) / 1024;   // scan blocks (98 <= 128)
    int NBUK = (N + 511) / 512;     // dst buckets (196 <= 256)

    degree_kernel<<<(E + 255) / 256, 256, 0, stream>>>(col, degi, E);
    dinv_kernel<<<(N + 255) / 256, 256, 0, stream>>>(degi, dinv, N);
    blockreduce_kernel<<<NB, 256, 0, stream>>>(degi, bsums, N);
    blockscan_kernel<<<1, 128, 0, stream>>>(bsums, boffs, offs + N, NB);
    scanapply_kernel<<<NB, 1024, 0, stream>>>(degi, boffs, offs, N);

    cursorinit_kernel<<<(NBUK + 255) / 256, 256, 0, stream>>>(offs, cursor, NBUK);
    partition_kernel<<<(E + EPW - 1) / EPW, 256, 0, stream>>>(row, col, cursor, pairs, E, NBUK);
    place_kernel<<<NBUK, 256, 0, stream>>>(pairs, offs, dinv, srcs, wgts, N);

    // conversions / weight packing
    int n4 = N * 128 / 4;
    f2bf_kernel<<<(n4 + 255) / 256, 256, 0, stream>>>(x, x_bf, n4);
    packW_kernel<<<8, 256, 0, stream>>>(W1, Wp1);
    packW_kernel<<<8, 256, 0, stream>>>(W2, Wp2);
    packW_kernel<<<8, 256, 0, stream>>>(W3, Wp3);

    int gemmBlocks = (N + 127) / 128;
    int aggBlocks  = (N + 3) / 4;   // 4 waves/block, wave per node

    gemm_mfma_kernel<<<gemmBlocks, 256, 0, stream>>>(x_bf, Wp1, hA, N);
    agg_kernel<<<aggBlocks, 256, 0, stream>>>(hA, offs, srcs, wgts, dinv, b1, hB, N);

    gemm_mfma_kernel<<<gemmBlocks, 256, 0, stream>>>(hB, Wp2, hA, N);
    agg_kernel<<<aggBlocks, 256, 0, stream>>>(hA, offs, srcs, wgts, dinv, b2, hB, N);

    gemm_mfma_kernel<<<gemmBlocks, 256, 0, stream>>>(hB, Wp3, hA, N);
    agg_kernel<<<aggBlocks, 256, 0, stream>>>(hA, offs, srcs, wgts, dinv, b3, hB, N);

    pool_kernel<<<NG, 128, 0, stream>>>(hB, batch, pooled, N);
    mlp_kernel<<<NG, 64, 0, stream>>>(pooled, Wm1, bm1, Wm2, bm2, out);
}

// Round 6
// 489.436 us; speedup vs baseline: 1.3575x; 1.2056x over previous
//
#include <hip/hip_runtime.h>
#include <hip/hip_bf16.h>

static constexpr int NG = 512;   // NUM_GRAPHS

typedef __attribute__((ext_vector_type(8))) short bf16x8;
typedef __attribute__((ext_vector_type(4))) float f32x4;

__device__ inline ushort f2bf(float f) {
    union { float f; uint u; } v; v.f = f;
    uint r = (v.u + 0x7FFF + ((v.u >> 16) & 1)) >> 16;   // RNE
    return (ushort)r;
}
__device__ inline float bf2f(ushort h) {
    union { uint u; float f; } v; v.u = (uint)h << 16;
    return v.f;
}
__device__ inline float bflo(uint g) { return bf2f((ushort)(g & 0xFFFF)); }
__device__ inline float bfhi(uint g) { return bf2f((ushort)(g >> 16)); }

// ---------------- degree / dinv ----------------
__global__ void degree_kernel(const int* __restrict__ col, int* __restrict__ degi, int E) {
    int e = blockIdx.x * blockDim.x + threadIdx.x;
    if (e < E) atomicAdd(&degi[col[e]], 1);
}

__global__ void dinv_kernel(const int* __restrict__ degi, float* __restrict__ dinv, int n) {
    int i = blockIdx.x * blockDim.x + threadIdx.x;
    if (i < n) dinv[i] = rsqrtf((float)(degi[i] + 1));  // +1 self loop; always > 0
}

// ---------------- hierarchical exclusive scan ----------------
__global__ __launch_bounds__(256) void blockreduce_kernel(const int* __restrict__ deg,
                                                          int* __restrict__ blocksums, int n) {
    __shared__ int lds[256];
    int b = blockIdx.x;
    int base = b * 1024;
    int s = 0;
    for (int j = threadIdx.x; j < 1024; j += 256) {
        int i = base + j;
        s += (i < n) ? deg[i] : 0;
    }
    lds[threadIdx.x] = s;
    __syncthreads();
    #pragma unroll
    for (int off = 128; off > 0; off >>= 1) {
        if ((int)threadIdx.x < off) lds[threadIdx.x] += lds[threadIdx.x + off];
        __syncthreads();
    }
    if (threadIdx.x == 0) blocksums[b] = lds[0];
}

__global__ __launch_bounds__(128) void blockscan_kernel(const int* __restrict__ blocksums,
                                                        int* __restrict__ blockoffs,
                                                        int* __restrict__ total_out, int nb) {
    __shared__ int lds[128];
    int v = ((int)threadIdx.x < nb) ? blocksums[threadIdx.x] : 0;
    lds[threadIdx.x] = v;
    __syncthreads();
    #pragma unroll
    for (int off = 1; off < 128; off <<= 1) {
        int t = ((int)threadIdx.x >= off) ? lds[threadIdx.x - off] : 0;
        __syncthreads();
        lds[threadIdx.x] += t;
        __syncthreads();
    }
    if ((int)threadIdx.x < nb) blockoffs[threadIdx.x] = lds[threadIdx.x] - v;  // exclusive
    if (threadIdx.x == 0) total_out[0] = lds[127];
}

__global__ __launch_bounds__(1024) void scanapply_kernel(const int* __restrict__ deg,
                                                         const int* __restrict__ blockoffs,
                                                         int* __restrict__ offsets, int n) {
    __shared__ int lds[1024];
    int b = blockIdx.x;
    int i = b * 1024 + (int)threadIdx.x;
    int v = (i < n) ? deg[i] : 0;
    lds[threadIdx.x] = v;
    __syncthreads();
    #pragma unroll
    for (int off = 1; off < 1024; off <<= 1) {
        int t = ((int)threadIdx.x >= off) ? lds[threadIdx.x - off] : 0;
        __syncthreads();
        lds[threadIdx.x] += t;
        __syncthreads();
    }
    if (i < n) offsets[i] = blockoffs[b] + lds[threadIdx.x] - v;
}

// ---------------- bucketed two-pass CSR build ----------------
__global__ __launch_bounds__(256) void cursorinit_kernel(const int* __restrict__ offs,
                                                         int* __restrict__ cursor, int nbuk) {
    int b = blockIdx.x * 256 + threadIdx.x;
    if (b < nbuk) cursor[b] = offs[b << 9];
}

static constexpr int EPW = 4096;   // edges per workgroup (16 per thread)
__global__ __launch_bounds__(256) void partition_kernel(const int* __restrict__ row,
                                                        const int* __restrict__ col,
                                                        int* __restrict__ cursor,
                                                        uint* __restrict__ pairs,
                                                        int E, int nbuk) {
    __shared__ int cnt[256];    // nbuk <= 256 (N <= 128K)
    __shared__ int gbase[256];
    int tid = threadIdx.x;
    int base = blockIdx.x * EPW;
    for (int b = tid; b < nbuk; b += 256) cnt[b] = 0;
    __syncthreads();
    int rank[16];
    #pragma unroll
    for (int j = 0; j < 16; j++) {
        int e = base + j * 256 + tid;
        rank[j] = (e < E) ? atomicAdd(&cnt[col[e] >> 9], 1) : 0;
    }
    __syncthreads();
    for (int b = tid; b < nbuk; b += 256)
        gbase[b] = cnt[b] ? atomicAdd(&cursor[b], cnt[b]) : 0;
    __syncthreads();
    #pragma unroll
    for (int j = 0; j < 16; j++) {
        int e = base + j * 256 + tid;
        if (e < E) {
            int d = col[e];
            int b = d >> 9;
            pairs[gbase[b] + rank[j]] = ((uint)row[e] << 9) | (uint)(d & 511);
        }
    }
}

__global__ __launch_bounds__(256) void place_kernel(const uint* __restrict__ pairs,
                                                    const int* __restrict__ offs,
                                                    const float* __restrict__ dinv,
                                                    int* __restrict__ srcs,
                                                    float* __restrict__ wgts, int N) {
    __shared__ int cur[512];
    int nodebase = blockIdx.x << 9;
    int nend = min(nodebase + 512, N);
    int lo = offs[nodebase], hi = offs[nend];
    cur[threadIdx.x] = 0;
    cur[threadIdx.x + 256] = 0;
    __syncthreads();
    for (int e = lo + (int)threadIdx.x; e < hi; e += 256) {
        uint p = pairs[e];
        int dloc = (int)(p & 511);
        int s = (int)(p >> 9);
        int d = nodebase + dloc;
        int pos = offs[d] + atomicAdd(&cur[dloc], 1);
        srcs[pos] = s;
        wgts[pos] = dinv[s] * dinv[d];
    }
}

// ---------------- f32 -> bf16 convert (x) ----------------
__global__ void f2bf_kernel(const float* __restrict__ in, ushort* __restrict__ out, int n4) {
    int i = blockIdx.x * blockDim.x + threadIdx.x;   // one float4 per thread
    if (i >= n4) return;
    float4 v = ((const float4*)in)[i];
    ushort4 o;
    o.x = f2bf(v.x); o.y = f2bf(v.y); o.z = f2bf(v.z); o.w = f2bf(v.w);
    ((ushort4*)out)[i] = o;
}

// ---------------- pack W (f32 row-major 128x128) into MFMA B-fragment layout ----------------
__global__ __launch_bounds__(256) void packW_kernel(const float* __restrict__ W,
                                                    ushort* __restrict__ Wp) {
    int idx = blockIdx.x * 256 + threadIdx.x;   // 0..2047
    int lane = idx & 63;
    int nt = (idx >> 6) & 7;
    int kt = idx >> 9;
    int col = nt * 16 + (lane & 15);
    int kbase = kt * 32 + (lane >> 4) * 8;
    ushort* dst = Wp + (size_t)idx * 8;
    #pragma unroll
    for (int j = 0; j < 8; j++)
        dst[j] = f2bf(W[(size_t)(kbase + j) * 128 + col]);
}

// ---------------- MFMA GEMM: C[Mx128](bf16) = A[Mx128](bf16) * W(packed bf16) ---------
__global__ __launch_bounds__(256) void gemm_mfma_kernel(const ushort* __restrict__ A,
                                                        const ushort* __restrict__ Wp,
                                                        ushort* __restrict__ C, int M) {
    int wave = threadIdx.x >> 6;
    int lane = threadIdx.x & 63;
    int r0 = blockIdx.x * 128 + wave * 32;
    if (r0 >= M) return;
    const int lrow = lane & 15;
    const int koff = (lane >> 4) * 8;
    f32x4 acc[2][8] = {};
    #pragma unroll
    for (int kt = 0; kt < 4; kt++) {
        bf16x8 a[2];
        #pragma unroll
        for (int m = 0; m < 2; m++) {
            int r = r0 + 16 * m + lrow;
            r = (r < M) ? r : (M - 1);
            a[m] = *(const bf16x8*)(A + (size_t)r * 128 + kt * 32 + koff);
        }
        #pragma unroll
        for (int nt = 0; nt < 8; nt++) {
            bf16x8 b = *(const bf16x8*)(Wp + ((size_t)(kt * 8 + nt) * 64 + lane) * 8);
            acc[0][nt] = __builtin_amdgcn_mfma_f32_16x16x32_bf16(a[0], b, acc[0][nt], 0, 0, 0);
            acc[1][nt] = __builtin_amdgcn_mfma_f32_16x16x32_bf16(a[1], b, acc[1][nt], 0, 0, 0);
        }
    }
    // C/D layout: col = lane&15, row = (lane>>4)*4 + reg   [verified m89]
    #pragma unroll
    for (int m = 0; m < 2; m++) {
        int rbase = r0 + 16 * m + (lane >> 4) * 4;
        int c0 = lane & 15;
        #pragma unroll
        for (int nt = 0; nt < 8; nt++) {
            #pragma unroll
            for (int r = 0; r < 4; r++) {
                int rr = rbase + r;
                if (rr < M) C[(size_t)rr * 128 + nt * 16 + c0] = f2bf(acc[m][nt][r]);
            }
        }
    }
}

// ---------------- aggregation (bf16 h, f32 accumulate, bf16 out) ----------------
// one wave per node; 8/4/1-unrolled edge loop -> up to 8 outstanding row gathers
__global__ __launch_bounds__(256) void agg_kernel(const ushort* __restrict__ h,
                                                  const int* __restrict__ offsets,
                                                  const int* __restrict__ srcs,
                                                  const float* __restrict__ wgts,
                                                  const float* __restrict__ dinv,
                                                  const float* __restrict__ bias,
                                                  ushort* __restrict__ out, int n) {
    int wid  = (int)((blockIdx.x * blockDim.x + threadIdx.x) >> 6);
    int lane = threadIdx.x & 63;
    if (wid >= n) return;
    int s0 = offsets[wid], s1 = offsets[wid + 1];
    float di = dinv[wid];
    const uint* hrow = (const uint*)h;
    uint hv = hrow[(size_t)wid * 64 + lane];
    float wself = di * di;
    float ax = wself * bflo(hv), ay = wself * bfhi(hv);
    float bx = 0.0f, by = 0.0f;
    int e = s0;
    for (; e + 8 <= s1; e += 8) {
        int   sI[8];
        float wI[8];
        uint  gI[8];
        #pragma unroll
        for (int j = 0; j < 8; j++) sI[j] = srcs[e + j];
        #pragma unroll
        for (int j = 0; j < 8; j++) wI[j] = wgts[e + j];
        #pragma unroll
        for (int j = 0; j < 8; j++) gI[j] = hrow[(size_t)sI[j] * 64 + lane];
        #pragma unroll
        for (int j = 0; j < 8; j += 2) {
            ax = fmaf(wI[j],   bflo(gI[j]),   ax);
            ay = fmaf(wI[j],   bfhi(gI[j]),   ay);
            bx = fmaf(wI[j+1], bflo(gI[j+1]), bx);
            by = fmaf(wI[j+1], bfhi(gI[j+1]), by);
        }
    }
    if (e + 4 <= s1) {
        int   sI[4];
        float wI[4];
        uint  gI[4];
        #pragma unroll
        for (int j = 0; j < 4; j++) sI[j] = srcs[e + j];
        #pragma unroll
        for (int j = 0; j < 4; j++) wI[j] = wgts[e + j];
        #pragma unroll
        for (int j = 0; j < 4; j++) gI[j] = hrow[(size_t)sI[j] * 64 + lane];
        #pragma unroll
        for (int j = 0; j < 4; j += 2) {
            ax = fmaf(wI[j],   bflo(gI[j]),   ax);
            ay = fmaf(wI[j],   bfhi(gI[j]),   ay);
            bx = fmaf(wI[j+1], bflo(gI[j+1]), bx);
            by = fmaf(wI[j+1], bfhi(gI[j+1]), by);
        }
        e += 4;
    }
    for (; e < s1; e++) {
        int s   = srcs[e];
        float w = wgts[e];
        uint g = hrow[(size_t)s * 64 + lane];
        ax = fmaf(w, bflo(g), ax);
        ay = fmaf(w, bfhi(g), ay);
    }
    ax += bx; ay += by;
    ax += bias[2 * lane];
    ay += bias[2 * lane + 1];
    ax = fmaxf(ax, 0.0f);
    ay = fmaxf(ay, 0.0f);
    ((uint*)(out + (size_t)wid * 128))[lane] = (uint)f2bf(ax) | ((uint)f2bf(ay) << 16);
}

// ---------------- mean pool per graph (batch sorted, bf16 in, f32 out) ----------------
__global__ __launch_bounds__(128) void pool_kernel(const ushort* __restrict__ h,
                                                   const int* __restrict__ batch,
                                                   float* __restrict__ pooled, int n) {
    int g = blockIdx.x;
    int lo = 0, hi = n;
    while (lo < hi) { int mid = (lo + hi) >> 1; if (batch[mid] < g) lo = mid + 1; else hi = mid; }
    int start = lo;
    lo = 0; hi = n;
    while (lo < hi) { int mid = (lo + hi) >> 1; if (batch[mid] < g + 1) lo = mid + 1; else hi = mid; }
    int end = lo;
    int c = threadIdx.x;
    float acc = 0.0f;
    for (int i = start; i < end; i++) acc += bf2f(h[(size_t)i * 128 + c]);
    float cnt = (float)(end - start);
    pooled[(size_t)g * 128 + c] = acc / fmaxf(cnt, 1.0f);
}

// ---------------- MLP ----------------
__global__ __launch_bounds__(64) void mlp_kernel(const float* __restrict__ pooled,
                                                 const float* __restrict__ Wm1,
                                                 const float* __restrict__ bm1,
                                                 const float* __restrict__ Wm2,
                                                 const float* __restrict__ bm2,
                                                 float* __restrict__ out) {
    int g = blockIdx.x;
    __shared__ float p[128];
    __shared__ float z[64];
    int t = threadIdx.x;
    p[t]      = pooled[(size_t)g * 128 + t];
    p[t + 64] = pooled[(size_t)g * 128 + 64 + t];
    __syncthreads();
    float acc = bm1[t];
    #pragma unroll 8
    for (int k = 0; k < 128; k++) acc = fmaf(p[k], Wm1[k * 64 + t], acc);
    z[t] = fmaxf(acc, 0.0f);
    __syncthreads();
    if (t < 32) {
        float o = bm2[t];
        #pragma unroll 8
        for (int k = 0; k < 64; k++) o = fmaf(z[k], Wm2[k * 32 + t], o);
        out[(size_t)g * 32 + t] = o;
    }
}

extern "C" void kernel_launch(void* const* d_in, const int* in_sizes, int n_in,
                              void* d_out, int out_size, void* d_ws, size_t ws_size,
                              hipStream_t stream) {
    const float* x    = (const float*)d_in[0];
    const int*   ei   = (const int*)d_in[1];
    const int*   batch= (const int*)d_in[2];
    const float* W1   = (const float*)d_in[3];
    const float* b1   = (const float*)d_in[4];
    const float* W2   = (const float*)d_in[5];
    const float* b2   = (const float*)d_in[6];
    const float* W3   = (const float*)d_in[7];
    const float* b3   = (const float*)d_in[8];
    const float* Wm1  = (const float*)d_in[9];
    const float* bm1  = (const float*)d_in[10];
    const float* Wm2  = (const float*)d_in[11];
    const float* bm2  = (const float*)d_in[12];
    float* out = (float*)d_out;

    int N = in_sizes[0] / 128;
    int E = in_sizes[1] / 2;
    const int* row = ei;       // sources
    const int* col = ei + E;   // targets

    char* w = (char*)d_ws;
    auto alloc = [&](size_t bytes) -> char* {
        char* p = w;
        w += (bytes + 255) & ~(size_t)255;
        return p;
    };
    int*    degi    = (int*)   alloc((size_t)N * 4);
    int*    offs    = (int*)   alloc((size_t)(N + 1) * 4);
    int*    cursor  = (int*)   alloc((size_t)N * 4);
    float*  dinv    = (float*) alloc((size_t)N * 4);
    int*    srcs    = (int*)   alloc((size_t)E * 4);
    float*  wgts    = (float*) alloc((size_t)E * 4);
    uint*   pairs   = (uint*)  alloc((size_t)E * 4);
    ushort* x_bf    = (ushort*)alloc((size_t)N * 128 * 2);
    ushort* hA      = (ushort*)alloc((size_t)N * 128 * 2);
    ushort* hB      = (ushort*)alloc((size_t)N * 128 * 2);
    float*  pooled  = (float*) alloc((size_t)NG * 128 * 4);
    int*    bsums   = (int*)   alloc((size_t)128 * 4);
    int*    boffs   = (int*)   alloc((size_t)128 * 4);
    ushort* Wp1     = (ushort*)alloc((size_t)128 * 128 * 2);
    ushort* Wp2     = (ushort*)alloc((size_t)128 * 128 * 2);
    ushort* Wp3     = (ushort*)alloc((size_t)128 * 128 * 2);
    (void)ws_size; (void)n_in; (void)out_size;

    hipMemsetAsync(degi, 0, (size_t)N * 4, stream);

    int NB   = (N + 1023) / 1024;   // scan blocks (98 <= 128)
    int NBUK = (N + 511) / 512;     // dst buckets (196 <= 256)

    degree_kernel<<<(E + 255) / 256, 256, 0, stream>>>(col, degi, E);
    dinv_kernel<<<(N + 255) / 256, 256, 0, stream>>>(degi, dinv, N);
    blockreduce_kernel<<<NB, 256, 0, stream>>>(degi, bsums, N);
    blockscan_kernel<<<1, 128, 0, stream>>>(bsums, boffs, offs + N, NB);
    scanapply_kernel<<<NB, 1024, 0, stream>>>(degi, boffs, offs, N);

    cursorinit_kernel<<<(NBUK + 255) / 256, 256, 0, stream>>>(offs, cursor, NBUK);
    partition_kernel<<<(E + EPW - 1) / EPW, 256, 0, stream>>>(row, col, cursor, pairs, E, NBUK);
    place_kernel<<<NBUK, 256, 0, stream>>>(pairs, offs, dinv, srcs, wgts, N);

    // conversions / weight packing
    int n4 = N * 128 / 4;
    f2bf_kernel<<<(n4 + 255) / 256, 256, 0, stream>>>(x, x_bf, n4);
    packW_kernel<<<8, 256, 0, stream>>>(W1, Wp1);
    packW_kernel<<<8, 256, 0, stream>>>(W2, Wp2);
    packW_kernel<<<8, 256, 0, stream>>>(W3, Wp3);

    int gemmBlocks = (N + 127) / 128;
    int aggBlocks  = (N + 3) / 4;   // 4 waves/block, wave per node

    gemm_mfma_kernel<<<gemmBlocks, 256, 0, stream>>>(x_bf, Wp1, hA, N);
    agg_kernel<<<aggBlocks, 256, 0, stream>>>(hA, offs, srcs, wgts, dinv, b1, hB, N);

    gemm_mfma_kernel<<<gemmBlocks, 256, 0, stream>>>(hB, Wp2, hA, N);
    agg_kernel<<<aggBlocks, 256, 0, stream>>>(hA, offs, srcs, wgts, dinv, b2, hB, N);

    gemm_mfma_kernel<<<gemmBlocks, 256, 0, stream>>>(hB, Wp3, hA, N);
    agg_kernel<<<aggBlocks, 256, 0, stream>>>(hA, offs, srcs, wgts, dinv, b3, hB, N);

    pool_kernel<<<NG, 128, 0, stream>>>(hB, batch, pooled, N);
    mlp_kernel<<<NG, 64, 0, stream>>>(pooled, Wm1, bm1, Wm2, bm2, out);
}

// Round 7
// 429.845 us; speedup vs baseline: 1.5456x; 1.1386x over previous
//
#include <hip/hip_runtime.h>
#include <hip/hip_bf16.h>

static constexpr int NG = 512;   // NUM_GRAPHS

typedef __attribute__((ext_vector_type(8))) short bf16x8;
typedef __attribute__((ext_vector_type(4))) float f32x4;

__device__ inline ushort f2bf(float f) {
    union { float f; uint u; } v; v.f = f;
    uint r = (v.u + 0x7FFF + ((v.u >> 16) & 1)) >> 16;   // RNE
    return (ushort)r;
}
__device__ inline float bf2f(ushort h) {
    union { uint u; float f; } v; v.u = (uint)h << 16;
    return v.f;
}
__device__ inline float bflo(uint g) { return bf2f((ushort)(g & 0xFFFF)); }
__device__ inline float bfhi(uint g) { return bf2f((ushort)(g >> 16)); }

// ---------------- degree / dinv ----------------
__global__ void degree_kernel(const int* __restrict__ col, int* __restrict__ degi, int E) {
    int e = blockIdx.x * blockDim.x + threadIdx.x;
    if (e < E) atomicAdd(&degi[col[e]], 1);
}

__global__ void dinv_kernel(const int* __restrict__ degi, float* __restrict__ dinv, int n) {
    int i = blockIdx.x * blockDim.x + threadIdx.x;
    if (i < n) dinv[i] = rsqrtf((float)(degi[i] + 1));  // +1 self loop; always > 0
}

// ---------------- hierarchical exclusive scan ----------------
__global__ __launch_bounds__(256) void blockreduce_kernel(const int* __restrict__ deg,
                                                          int* __restrict__ blocksums, int n) {
    __shared__ int lds[256];
    int b = blockIdx.x;
    int base = b * 1024;
    int s = 0;
    for (int j = threadIdx.x; j < 1024; j += 256) {
        int i = base + j;
        s += (i < n) ? deg[i] : 0;
    }
    lds[threadIdx.x] = s;
    __syncthreads();
    #pragma unroll
    for (int off = 128; off > 0; off >>= 1) {
        if ((int)threadIdx.x < off) lds[threadIdx.x] += lds[threadIdx.x + off];
        __syncthreads();
    }
    if (threadIdx.x == 0) blocksums[b] = lds[0];
}

__global__ __launch_bounds__(128) void blockscan_kernel(const int* __restrict__ blocksums,
                                                        int* __restrict__ blockoffs,
                                                        int* __restrict__ total_out, int nb) {
    __shared__ int lds[128];
    int v = ((int)threadIdx.x < nb) ? blocksums[threadIdx.x] : 0;
    lds[threadIdx.x] = v;
    __syncthreads();
    #pragma unroll
    for (int off = 1; off < 128; off <<= 1) {
        int t = ((int)threadIdx.x >= off) ? lds[threadIdx.x - off] : 0;
        __syncthreads();
        lds[threadIdx.x] += t;
        __syncthreads();
    }
    if ((int)threadIdx.x < nb) blockoffs[threadIdx.x] = lds[threadIdx.x] - v;  // exclusive
    if (threadIdx.x == 0) total_out[0] = lds[127];
}

__global__ __launch_bounds__(1024) void scanapply_kernel(const int* __restrict__ deg,
                                                         const int* __restrict__ blockoffs,
                                                         int* __restrict__ offsets, int n) {
    __shared__ int lds[1024];
    int b = blockIdx.x;
    int i = b * 1024 + (int)threadIdx.x;
    int v = (i < n) ? deg[i] : 0;
    lds[threadIdx.x] = v;
    __syncthreads();
    #pragma unroll
    for (int off = 1; off < 1024; off <<= 1) {
        int t = ((int)threadIdx.x >= off) ? lds[threadIdx.x - off] : 0;
        __syncthreads();
        lds[threadIdx.x] += t;
        __syncthreads();
    }
    if (i < n) offsets[i] = blockoffs[b] + lds[threadIdx.x] - v;
}

// ---------------- bucketed two-pass CSR build ----------------
__global__ __launch_bounds__(256) void cursorinit_kernel(const int* __restrict__ offs,
                                                         int* __restrict__ cursor, int nbuk) {
    int b = blockIdx.x * 256 + threadIdx.x;
    if (b < nbuk) cursor[b] = offs[b << 9];
}

static constexpr int EPW = 4096;   // edges per workgroup (16 per thread)
__global__ __launch_bounds__(256) void partition_kernel(const int* __restrict__ row,
                                                        const int* __restrict__ col,
                                                        int* __restrict__ cursor,
                                                        uint* __restrict__ pairs,
                                                        int E, int nbuk) {
    __shared__ int cnt[256];    // nbuk <= 256 (N <= 128K)
    __shared__ int gbase[256];
    int tid = threadIdx.x;
    int base = blockIdx.x * EPW;
    for (int b = tid; b < nbuk; b += 256) cnt[b] = 0;
    __syncthreads();
    int rank[16];
    #pragma unroll
    for (int j = 0; j < 16; j++) {
        int e = base + j * 256 + tid;
        rank[j] = (e < E) ? atomicAdd(&cnt[col[e] >> 9], 1) : 0;
    }
    __syncthreads();
    for (int b = tid; b < nbuk; b += 256)
        gbase[b] = cnt[b] ? atomicAdd(&cursor[b], cnt[b]) : 0;
    __syncthreads();
    #pragma unroll
    for (int j = 0; j < 16; j++) {
        int e = base + j * 256 + tid;
        if (e < E) {
            int d = col[e];
            int b = d >> 9;
            pairs[gbase[b] + rank[j]] = ((uint)row[e] << 9) | (uint)(d & 511);
        }
    }
}

__global__ __launch_bounds__(256) void place_kernel(const uint* __restrict__ pairs,
                                                    const int* __restrict__ offs,
                                                    const float* __restrict__ dinv,
                                                    int* __restrict__ srcs,
                                                    float* __restrict__ wgts, int N) {
    __shared__ int cur[512];
    int nodebase = blockIdx.x << 9;
    int nend = min(nodebase + 512, N);
    int lo = offs[nodebase], hi = offs[nend];
    cur[threadIdx.x] = 0;
    cur[threadIdx.x + 256] = 0;
    __syncthreads();
    for (int e = lo + (int)threadIdx.x; e < hi; e += 256) {
        uint p = pairs[e];
        int dloc = (int)(p & 511);
        int s = (int)(p >> 9);
        int d = nodebase + dloc;
        int pos = offs[d] + atomicAdd(&cur[dloc], 1);
        srcs[pos] = s;
        wgts[pos] = dinv[s] * dinv[d];
    }
}

// ---------------- f32 -> bf16 convert (x) ----------------
__global__ void f2bf_kernel(const float* __restrict__ in, ushort* __restrict__ out, int n4) {
    int i = blockIdx.x * blockDim.x + threadIdx.x;   // one float4 per thread
    if (i >= n4) return;
    float4 v = ((const float4*)in)[i];
    ushort4 o;
    o.x = f2bf(v.x); o.y = f2bf(v.y); o.z = f2bf(v.z); o.w = f2bf(v.w);
    ((ushort4*)out)[i] = o;
}

// ---------------- pack W (f32 row-major 128x128) into MFMA B-fragment layout ----------------
__global__ __launch_bounds__(256) void packW_kernel(const float* __restrict__ W,
                                                    ushort* __restrict__ Wp) {
    int idx = blockIdx.x * 256 + threadIdx.x;   // 0..2047
    int lane = idx & 63;
    int nt = (idx >> 6) & 7;
    int kt = idx >> 9;
    int col = nt * 16 + (lane & 15);
    int kbase = kt * 32 + (lane >> 4) * 8;
    ushort* dst = Wp + (size_t)idx * 8;
    #pragma unroll
    for (int j = 0; j < 8; j++)
        dst[j] = f2bf(W[(size_t)(kbase + j) * 128 + col]);
}

// ---------------- MFMA GEMM: C[Mx128](bf16) = A[Mx128](bf16) * W(packed bf16) ---------
__global__ __launch_bounds__(256) void gemm_mfma_kernel(const ushort* __restrict__ A,
                                                        const ushort* __restrict__ Wp,
                                                        ushort* __restrict__ C, int M) {
    int wave = threadIdx.x >> 6;
    int lane = threadIdx.x & 63;
    int r0 = blockIdx.x * 128 + wave * 32;
    if (r0 >= M) return;
    const int lrow = lane & 15;
    const int koff = (lane >> 4) * 8;
    f32x4 acc[2][8] = {};
    #pragma unroll
    for (int kt = 0; kt < 4; kt++) {
        bf16x8 a[2];
        #pragma unroll
        for (int m = 0; m < 2; m++) {
            int r = r0 + 16 * m + lrow;
            r = (r < M) ? r : (M - 1);
            a[m] = *(const bf16x8*)(A + (size_t)r * 128 + kt * 32 + koff);
        }
        #pragma unroll
        for (int nt = 0; nt < 8; nt++) {
            bf16x8 b = *(const bf16x8*)(Wp + ((size_t)(kt * 8 + nt) * 64 + lane) * 8);
            acc[0][nt] = __builtin_amdgcn_mfma_f32_16x16x32_bf16(a[0], b, acc[0][nt], 0, 0, 0);
            acc[1][nt] = __builtin_amdgcn_mfma_f32_16x16x32_bf16(a[1], b, acc[1][nt], 0, 0, 0);
        }
    }
    // C/D layout: col = lane&15, row = (lane>>4)*4 + reg   [verified m89]
    #pragma unroll
    for (int m = 0; m < 2; m++) {
        int rbase = r0 + 16 * m + (lane >> 4) * 4;
        int c0 = lane & 15;
        #pragma unroll
        for (int nt = 0; nt < 8; nt++) {
            #pragma unroll
            for (int r = 0; r < 4; r++) {
                int rr = rbase + r;
                if (rr < M) C[(size_t)rr * 128 + nt * 16 + c0] = f2bf(acc[m][nt][r]);
            }
        }
    }
}

// ---------------- aggregation (bf16 h, f32 accumulate, bf16 out) ----------------
// one wave per node; 8/4/1-unrolled edge loop -> up to 8 outstanding row gathers
__global__ __launch_bounds__(256) void agg_kernel(const ushort* __restrict__ h,
                                                  const int* __restrict__ offsets,
                                                  const int* __restrict__ srcs,
                                                  const float* __restrict__ wgts,
                                                  const float* __restrict__ dinv,
                                                  const float* __restrict__ bias,
                                                  ushort* __restrict__ out, int n) {
    int wid  = (int)((blockIdx.x * blockDim.x + threadIdx.x) >> 6);
    int lane = threadIdx.x & 63;
    if (wid >= n) return;
    int s0 = offsets[wid], s1 = offsets[wid + 1];
    float di = dinv[wid];
    const uint* hrow = (const uint*)h;
    uint hv = hrow[(size_t)wid * 64 + lane];
    float wself = di * di;
    float ax = wself * bflo(hv), ay = wself * bfhi(hv);
    float bx = 0.0f, by = 0.0f;
    int e = s0;
    for (; e + 8 <= s1; e += 8) {
        int   sI[8];
        float wI[8];
        uint  gI[8];
        #pragma unroll
        for (int j = 0; j < 8; j++) sI[j] = srcs[e + j];
        #pragma unroll
        for (int j = 0; j < 8; j++) wI[j] = wgts[e + j];
        #pragma unroll
        for (int j = 0; j < 8; j++) gI[j] = hrow[(size_t)sI[j] * 64 + lane];
        #pragma unroll
        for (int j = 0; j < 8; j += 2) {
            ax = fmaf(wI[j],   bflo(gI[j]),   ax);
            ay = fmaf(wI[j],   bfhi(gI[j]),   ay);
            bx = fmaf(wI[j+1], bflo(gI[j+1]), bx);
            by = fmaf(wI[j+1], bfhi(gI[j+1]), by);
        }
    }
    if (e + 4 <= s1) {
        int   sI[4];
        float wI[4];
        uint  gI[4];
        #pragma unroll
        for (int j = 0; j < 4; j++) sI[j] = srcs[e + j];
        #pragma unroll
        for (int j = 0; j < 4; j++) wI[j] = wgts[e + j];
        #pragma unroll
        for (int j = 0; j < 4; j++) gI[j] = hrow[(size_t)sI[j] * 64 + lane];
        #pragma unroll
        for (int j = 0; j < 4; j += 2) {
            ax = fmaf(wI[j],   bflo(gI[j]),   ax);
            ay = fmaf(wI[j],   bfhi(gI[j]),   ay);
            bx = fmaf(wI[j+1], bflo(gI[j+1]), bx);
            by = fmaf(wI[j+1], bfhi(gI[j+1]), by);
        }
        e += 4;
    }
    for (; e < s1; e++) {
        int s   = srcs[e];
        float w = wgts[e];
        uint g = hrow[(size_t)s * 64 + lane];
        ax = fmaf(w, bflo(g), ax);
        ay = fmaf(w, bfhi(g), ay);
    }
    ax += bx; ay += by;
    ax += bias[2 * lane];
    ay += bias[2 * lane + 1];
    ax = fmaxf(ax, 0.0f);
    ay = fmaxf(ay, 0.0f);
    ((uint*)(out + (size_t)wid * 128))[lane] = (uint)f2bf(ax) | ((uint)f2bf(ay) << 16);
}

// ---------------- mean pool per graph (batch sorted, bf16 in, f32 out) ----------------
// one block (8 waves) per graph; thread (rg,c2)=(t>>6,t&63): channels 2c2,2c2+1,
// rows start+rg, +8, ... ; 4-deep unroll; fixed-order LDS reduce (deterministic)
__global__ __launch_bounds__(512) void pool_kernel(const ushort* __restrict__ h,
                                                   const int* __restrict__ batch,
                                                   float* __restrict__ pooled, int n) {
    int g = blockIdx.x;
    int lo = 0, hi = n;
    while (lo < hi) { int mid = (lo + hi) >> 1; if (batch[mid] < g) lo = mid + 1; else hi = mid; }
    int start = lo;
    lo = 0; hi = n;
    while (lo < hi) { int mid = (lo + hi) >> 1; if (batch[mid] < g + 1) lo = mid + 1; else hi = mid; }
    int end = lo;

    int t  = threadIdx.x;
    int c2 = t & 63;    // uint index -> channels 2*c2, 2*c2+1
    int rg = t >> 6;    // row group 0..7
    const uint* hu = (const uint*)h;
    float sx = 0.0f, sy = 0.0f;
    int i = start + rg;
    for (; i + 24 < end; i += 32) {
        uint g0 = hu[(size_t)i * 64 + c2];
        uint g1 = hu[(size_t)(i + 8) * 64 + c2];
        uint g2 = hu[(size_t)(i + 16) * 64 + c2];
        uint g3 = hu[(size_t)(i + 24) * 64 + c2];
        sx += bflo(g0); sy += bfhi(g0);
        sx += bflo(g1); sy += bfhi(g1);
        sx += bflo(g2); sy += bfhi(g2);
        sx += bflo(g3); sy += bfhi(g3);
    }
    for (; i < end; i += 8) {
        uint gg = hu[(size_t)i * 64 + c2];
        sx += bflo(gg); sy += bfhi(gg);
    }
    __shared__ float lsx[512];
    __shared__ float lsy[512];
    lsx[t] = sx; lsy[t] = sy;
    __syncthreads();
    if (rg == 0) {
        float ax = lsx[c2], ay = lsy[c2];
        #pragma unroll
        for (int k = 1; k < 8; k++) {
            ax += lsx[c2 + 64 * k];
            ay += lsy[c2 + 64 * k];
        }
        float cnt = fmaxf((float)(end - start), 1.0f);
        pooled[(size_t)g * 128 + 2 * c2]     = ax / cnt;
        pooled[(size_t)g * 128 + 2 * c2 + 1] = ay / cnt;
    }
}

// ---------------- MLP ----------------
__global__ __launch_bounds__(64) void mlp_kernel(const float* __restrict__ pooled,
                                                 const float* __restrict__ Wm1,
                                                 const float* __restrict__ bm1,
                                                 const float* __restrict__ Wm2,
                                                 const float* __restrict__ bm2,
                                                 float* __restrict__ out) {
    int g = blockIdx.x;
    __shared__ float p[128];
    __shared__ float z[64];
    int t = threadIdx.x;
    p[t]      = pooled[(size_t)g * 128 + t];
    p[t + 64] = pooled[(size_t)g * 128 + 64 + t];
    __syncthreads();
    float acc = bm1[t];
    #pragma unroll 8
    for (int k = 0; k < 128; k++) acc = fmaf(p[k], Wm1[k * 64 + t], acc);
    z[t] = fmaxf(acc, 0.0f);
    __syncthreads();
    if (t < 32) {
        float o = bm2[t];
        #pragma unroll 8
        for (int k = 0; k < 64; k++) o = fmaf(z[k], Wm2[k * 32 + t], o);
        out[(size_t)g * 32 + t] = o;
    }
}

extern "C" void kernel_launch(void* const* d_in, const int* in_sizes, int n_in,
                              void* d_out, int out_size, void* d_ws, size_t ws_size,
                              hipStream_t stream) {
    const float* x    = (const float*)d_in[0];
    const int*   ei   = (const int*)d_in[1];
    const int*   batch= (const int*)d_in[2];
    const float* W1   = (const float*)d_in[3];
    const float* b1   = (const float*)d_in[4];
    const float* W2   = (const float*)d_in[5];
    const float* b2   = (const float*)d_in[6];
    const float* W3   = (const float*)d_in[7];
    const float* b3   = (const float*)d_in[8];
    const float* Wm1  = (const float*)d_in[9];
    const float* bm1  = (const float*)d_in[10];
    const float* Wm2  = (const float*)d_in[11];
    const float* bm2  = (const float*)d_in[12];
    float* out = (float*)d_out;

    int N = in_sizes[0] / 128;
    int E = in_sizes[1] / 2;
    const int* row = ei;       // sources
    const int* col = ei + E;   // targets

    char* w = (char*)d_ws;
    auto alloc = [&](size_t bytes) -> char* {
        char* p = w;
        w += (bytes + 255) & ~(size_t)255;
        return p;
    };
    int*    degi    = (int*)   alloc((size_t)N * 4);
    int*    offs    = (int*)   alloc((size_t)(N + 1) * 4);
    int*    cursor  = (int*)   alloc((size_t)N * 4);
    float*  dinv    = (float*) alloc((size_t)N * 4);
    int*    srcs    = (int*)   alloc((size_t)E * 4);
    float*  wgts    = (float*) alloc((size_t)E * 4);
    uint*   pairs   = (uint*)  alloc((size_t)E * 4);
    ushort* x_bf    = (ushort*)alloc((size_t)N * 128 * 2);
    ushort* hA      = (ushort*)alloc((size_t)N * 128 * 2);
    ushort* hB      = (ushort*)alloc((size_t)N * 128 * 2);
    float*  pooled  = (float*) alloc((size_t)NG * 128 * 4);
    int*    bsums   = (int*)   alloc((size_t)128 * 4);
    int*    boffs   = (int*)   alloc((size_t)128 * 4);
    ushort* Wp1     = (ushort*)alloc((size_t)128 * 128 * 2);
    ushort* Wp2     = (ushort*)alloc((size_t)128 * 128 * 2);
    ushort* Wp3     = (ushort*)alloc((size_t)128 * 128 * 2);
    (void)ws_size; (void)n_in; (void)out_size;

    hipMemsetAsync(degi, 0, (size_t)N * 4, stream);

    int NB   = (N + 1023) / 1024;   // scan blocks (98 <= 128)
    int NBUK = (N + 511) / 512;     // dst buckets (196 <= 256)

    degree_kernel<<<(E + 255) / 256, 256, 0, stream>>>(col, degi, E);
    dinv_kernel<<<(N + 255) / 256, 256, 0, stream>>>(degi, dinv, N);
    blockreduce_kernel<<<NB, 256, 0, stream>>>(degi, bsums, N);
    blockscan_kernel<<<1, 128, 0, stream>>>(bsums, boffs, offs + N, NB);
    scanapply_kernel<<<NB, 1024, 0, stream>>>(degi, boffs, offs, N);

    cursorinit_kernel<<<(NBUK + 255) / 256, 256, 0, stream>>>(offs, cursor, NBUK);
    partition_kernel<<<(E + EPW - 1) / EPW, 256, 0, stream>>>(row, col, cursor, pairs, E, NBUK);
    place_kernel<<<NBUK, 256, 0, stream>>>(pairs, offs, dinv, srcs, wgts, N);

    // conversions / weight packing
    int n4 = N * 128 / 4;
    f2bf_kernel<<<(n4 + 255) / 256, 256, 0, stream>>>(x, x_bf, n4);
    packW_kernel<<<8, 256, 0, stream>>>(W1, Wp1);
    packW_kernel<<<8, 256, 0, stream>>>(W2, Wp2);
    packW_kernel<<<8, 256, 0, stream>>>(W3, Wp3);

    int gemmBlocks = (N + 127) / 128;
    int aggBlocks  = (N + 3) / 4;   // 4 waves/block, wave per node

    gemm_mfma_kernel<<<gemmBlocks, 256, 0, stream>>>(x_bf, Wp1, hA, N);
    agg_kernel<<<aggBlocks, 256, 0, stream>>>(hA, offs, srcs, wgts, dinv, b1, hB, N);

    gemm_mfma_kernel<<<gemmBlocks, 256, 0, stream>>>(hB, Wp2, hA, N);
    agg_kernel<<<aggBlocks, 256, 0, stream>>>(hA, offs, srcs, wgts, dinv, b2, hB, N);

    gemm_mfma_kernel<<<gemmBlocks, 256, 0, stream>>>(hB, Wp3, hA, N);
    agg_kernel<<<aggBlocks, 256, 0, stream>>>(hA, offs, srcs, wgts, dinv, b3, hB, N);

    pool_kernel<<<NG, 512, 0, stream>>>(hB, batch, pooled, N);
    mlp_kernel<<<NG, 64, 0, stream>>>(pooled, Wm1, bm1, Wm2, bm2, out);
}